// Round 1
// 333.856 us; speedup vs baseline: 1.2237x; 1.2237x over previous
//
#include <hip/hip_runtime.h>
#include <math.h>

#define ALPHA 0.42f
#define H 1024
#define W 1024
#define NB 16
#define NCH 48
#define BH 64           // rows per band (per block); 1024/64 * 48 = 768 blocks = 3/CU, one round

typedef float nfloat4 __attribute__((ext_vector_type(4)));

// native v_rcp_f32 (1 ulp) instead of IEEE divide (~9 instrs each)
__device__ __forceinline__ float sigf(float x) {
    return __builtin_amdgcn_rcpf(1.0f + __expf(-x));
}

// Cross-wave LDS handoff barrier that does NOT drain vmcnt: __syncthreads()
// would emit s_waitcnt vmcnt(0) before s_barrier and stall every row step on
// the in-flight global prefetch. lgkmcnt(0) makes this wave's ds_write visible
// (and retires its ds_reads) before the barrier; raw s_barrier leaves the
// global loads in flight. asm "memory" fences stop compiler reordering of the
// LDS ops across the barrier.
__device__ __forceinline__ void block_sync_lds() {
    asm volatile("s_waitcnt lgkmcnt(0)" ::: "memory");
    __builtin_amdgcn_s_barrier();
    asm volatile("" ::: "memory");
}

// ---------------------------------------------------------------------------
// score_kernel: register-rolling vertical walk; horizontal halo via a 2-slot
// LDS row ring with zero borders (replaces 6 shuffles + lane-0/63 halo loads).
// Wave w owns cols [256w,256w+256), lane owns 4 cols. Per row step:
//   sigmoid(vb) -> ds_write row -> issue prefetch row+2 -> barrier ->
//   2 aligned ds_read_b128 for cols [-4..-1] and [+4..+7] -> rolling sums ->
//   Sobel/Lap/variance emit for row-6.
// score = ALPHA*sum(edge) + (1-ALPHA)/49 * sum(fx*fy*(m-mean7x7)^2)
// ---------------------------------------------------------------------------
__global__ __launch_bounds__(256, 3)
void score_kernel(const float* __restrict__ logits, float* __restrict__ scores) {
    __shared__ __align__(16) float lrow[2][1032];   // col c at idx c+4; idx 0..3 & 1028..1031 stay 0
    __shared__ float red[4];
    const int tid  = threadIdx.x;
    const int lane = tid & 63;
    const int wvi  = tid >> 6;
    const int ch   = blockIdx.y;
    const int band = blockIdx.x * BH;
    const int c4   = wvi * 256 + lane * 4;
    const float* img   = logits + (size_t)ch * (H * W);
    const float* gbase = img + c4;

    if (tid < 8) {                                   // zero borders once (first barrier publishes)
        int idx = (tid & 3) + ((tid & 4) ? 1028 : 0);
        lrow[0][idx] = 0.f;
        lrow[1][idx] = 0.f;
    }

    // per-column variance counts, with (1-ALPHA)/49 folded in
    const float cvar  = (1.0f - ALPHA) * (1.0f / 49.0f);
    const float wfxc0 = cvar * (float)(7 - max(0, 3 - (c4 + 0)) - max(0, (c4 + 0) - (W - 4)));
    const float wfxc1 = cvar * (float)(7 - max(0, 3 - (c4 + 1)) - max(0, (c4 + 1) - (W - 4)));
    const float wfxc2 = cvar * (float)(7 - max(0, 3 - (c4 + 2)) - max(0, (c4 + 2) - (W - 4)));
    const float wfxc3 = cvar * (float)(7 - max(0, 3 - (c4 + 3)) - max(0, (c4 + 3) - (W - 4)));

    float4 vb[2];                                    // global prefetch ring, depth 2, distance 2
    float srm[8], sr0[8], sr1[8], sr2[8], sr3[8], srp[8];  // sigmoid rows, cols c-1..c+4
    float rsA[8], rsB[8], rsC[8], rsD[8];            // horizontal 7-sums ring
    float vs0 = 0.f, vs1 = 0.f, vs2 = 0.f, vs3 = 0.f, acc = 0.f;
    #pragma unroll
    for (int k = 0; k < 8; ++k) { rsA[k] = rsB[k] = rsC[k] = rsD[k] = 0.f; }

    auto LOADROW = [&](int g, int slot) {
        int gc = min(max(g, 0), H - 1);              // clamp; invalid rows zeroed at ingest
        vb[slot] = *(const float4*)(gbase + ((size_t)gc << 10));
    };

    auto STEP = [&](int n, int s8, int s2, bool doLoad, bool doEmit) {
        const int g = band - 3 + n;                  // row being ingested (wave-uniform)
        float4 raw = vb[s2];
        float q0 = 0.f, q1 = 0.f, q2 = 0.f, q3 = 0.f;
        if (g >= 0 && g < H) {
            q0 = sigf(raw.x); q1 = sigf(raw.y); q2 = sigf(raw.z); q3 = sigf(raw.w);
        }
        *(float4*)&lrow[s2][c4 + 4] = make_float4(q0, q1, q2, q3);
        if (doLoad) LOADROW(g + 2, s2);              // issue BEFORE barrier; stays in flight
        block_sync_lds();
        float4 hl = *(const float4*)&lrow[s2][c4];       // cols c4-4..c4-1 (x unused)
        float4 hr = *(const float4*)&lrow[s2][c4 + 8];   // cols c4+4..c4+7 (w unused)
        float l1 = hl.y, l2 = hl.z, l3 = hl.w;           // s[-3],s[-2],s[-1]
        float r0 = hr.x, r1 = hr.y, r2 = hr.z;           // s[+4],s[+5],s[+6]
        float a = ((l1 + l2) + (l3 + q0)) + ((q1 + q2) + q3);   // 7-window @ col c4
        float b = a - l1 + r0;
        float c = b - l2 + r1;
        float d = c - l3 + r2;
        const int old = (s8 + 1) & 7;                // row r-7 leaves the vertical window
        vs0 += a - rsA[old]; vs1 += b - rsB[old]; vs2 += c - rsC[old]; vs3 += d - rsD[old];
        rsA[s8] = a; rsB[s8] = b; rsC[s8] = c; rsD[s8] = d;
        srm[s8] = l3; sr0[s8] = q0; sr1[s8] = q1; sr2[s8] = q2; sr3[s8] = q3; srp[s8] = r0;
        if (doEmit) {                                // emit row y = band+n-6 = g-3
            const int Y = g - 3;
            float fy = (float)(7 - max(0, 3 - Y) - max(0, Y - (H - 4)));
            float wf0 = fy * wfxc0, wf1 = fy * wfxc1, wf2 = fy * wfxc2, wf3 = fy * wfxc3;
            const int sA = (s8 + 4) & 7, sB = (s8 + 5) & 7, sC = (s8 + 6) & 7;  // rows y-1,y,y+1
            float A0 = srm[sA], A1 = sr0[sA], A2 = sr1[sA], A3 = sr2[sA], A4 = sr3[sA], A5 = srp[sA];
            float B0 = srm[sB], B1 = sr0[sB], B2 = sr1[sB], B3 = sr2[sB], B4 = sr3[sB], B5 = srp[sB];
            float C0 = srm[sC], C1 = sr0[sC], C2 = sr1[sC], C3 = sr2[sC], C4 = sr3[sC], C5 = srp[sC];
            // shared row combos: t = top+bot, u = top-bot
            float t0 = A0 + C0, t1 = A1 + C1, t2 = A2 + C2, t3 = A3 + C3, t4 = A4 + C4, t5 = A5 + C5;
            float u0 = A0 - C0, u1 = A1 - C1, u2 = A2 - C2, u3 = A3 - C3, u4 = A4 - C4, u5 = A5 - C5;
            auto PIXF = [&](float tp, float tp1, float tp2, float Bp, float Bp1, float Bp2,
                            float up, float up1, float up2, float vsv, float wf) {
                float sgx = (tp - tp2) + 2.f * (Bp - Bp2);
                float sgy = (up + up2) + 2.f * up1;
                float lp  = (Bp + Bp2) + tp1 - 4.f * Bp1;
                float edge = __builtin_amdgcn_sqrtf(sgx * sgx + sgy * sgy) + 0.5f * fabsf(lp);
                float dd = Bp1 - vsv * (1.f / 49.f);
                acc += ALPHA * edge + wf * (dd * dd);
            };
            PIXF(t0, t1, t2, B0, B1, B2, u0, u1, u2, vs0, wf0);
            PIXF(t1, t2, t3, B1, B2, B3, u1, u2, u3, vs1, wf1);
            PIXF(t2, t3, t4, B2, B3, B4, u2, u3, u4, vs2, wf2);
            PIXF(t3, t4, t5, B3, B4, B5, u3, u4, u5, vs3, wf3);
        }
    };

    // 70 steps total: ingest rows band-3 .. band+66, emit rows band .. band+63
    LOADROW(band - 3, 0);
    LOADROW(band - 2, 1);
    STEP(0, 0, 0, true, false);
    STEP(1, 1, 1, true, false);
    STEP(2, 2, 0, true, false);
    STEP(3, 3, 1, true, false);
    STEP(4, 4, 0, true, false);
    STEP(5, 5, 1, true, false);
    STEP(6, 6, 0, true, true);
    STEP(7, 7, 1, true, true);
    #pragma unroll 1
    for (int nn = 8; nn < BH; nn += 8) {             // n = 8..63; slots depend only on k
        #pragma unroll
        for (int k = 0; k < 8; ++k)
            STEP(nn + k, k, k & 1, true, true);
    }
    STEP(BH + 0, 0, 0, true,  true);
    STEP(BH + 1, 1, 1, true,  true);
    STEP(BH + 2, 2, 0, true,  true);
    STEP(BH + 3, 3, 1, true,  true);
    STEP(BH + 4, 4, 0, false, true);
    STEP(BH + 5, 5, 1, false, true);

    #pragma unroll
    for (int off = 32; off > 0; off >>= 1) acc += __shfl_down(acc, off);
    if (lane == 0) red[wvi] = acc;
    __syncthreads();
    if (tid == 0) atomicAdd(&scores[ch], red[0] + red[1] + red[2] + red[3]);
}

// ---------------------------------------------------------------------------
// fuse_kernel: out[b] = sum_s w[b,s]*logits[b,s].
// b is block-uniform (block covers 1024 consecutive float4 inside one image),
// loads are cacheable (logits are LLC-resident after score_kernel; nt loads
// defeated that), stores stay nontemporal (out is never re-read; keep LLC for
// logits). 4 float4/thread -> 12 independent loads of ILP.
// ---------------------------------------------------------------------------
__global__ __launch_bounds__(256)
void fuse_kernel(const float* __restrict__ logits,
                 const float* __restrict__ scores,
                 const float* __restrict__ lw,
                 float* __restrict__ out) {
    const size_t HW4 = (size_t)(H * W) / 4;          // 2^18 float4 per image plane

    float l0 = lw[0], l1 = lw[1], l2 = lw[2];
    float mx = fmaxf(l0, fmaxf(l1, l2));
    float e0 = __expf(l0 - mx), e1 = __expf(l1 - mx), e2 = __expf(l2 - mx);
    float inv = __builtin_amdgcn_rcpf(e0 + e1 + e2);
    float wl0 = e0 * inv, wl1 = e1 * inv, wl2 = e2 * inv;

    const int b = blockIdx.x >> 8;                   // 4096 blocks, 1024 f4/block, uniform image id
    float s0 = scores[b * 3 + 0], s1 = scores[b * 3 + 1], s2 = scores[b * 3 + 2];
    float itot = __builtin_amdgcn_rcpf(s0 + s1 + s2 + 1e-6f);
    float w0 = 0.5f * (s0 * itot + wl0);
    float w1 = 0.5f * (s1 * itot + wl1);
    float w2 = 0.5f * (s2 * itot + wl2);

    size_t i0 = (size_t)blockIdx.x * 1024 + threadIdx.x;
    size_t r  = i0 & (HW4 - 1);
    const nfloat4* pb = (const nfloat4*)logits + (size_t)b * 3 * HW4 + r;
    nfloat4* po = (nfloat4*)out + i0;
    #pragma unroll
    for (int k = 0; k < 4; ++k) {
        nfloat4 x0 = pb[k * 256];
        nfloat4 x1 = pb[k * 256 + HW4];
        nfloat4 x2 = pb[k * 256 + 2 * HW4];
        nfloat4 o = x0 * w0 + x1 * w1 + x2 * w2;
        __builtin_nontemporal_store(o, po + k * 256);
    }
}

extern "C" void kernel_launch(void* const* d_in, const int* in_sizes, int n_in,
                              void* d_out, int out_size, void* d_ws, size_t ws_size,
                              hipStream_t stream) {
    const float* logits = (const float*)d_in[0];
    const float* lw     = (const float*)d_in[1];
    float* out    = (float*)d_out;
    float* scores = (float*)d_ws;    // 48 floats

    (void)hipMemsetAsync(d_ws, 0, NCH * sizeof(float), stream);

    dim3 g1(H / BH, NCH);            // (16, 48) = 768 blocks; 3/CU, fully resident in one round
    score_kernel<<<g1, 256, 0, stream>>>(logits, scores);

    fuse_kernel<<<4096, 256, 0, stream>>>(logits, scores, lw, out);
}